// Round 3
// baseline (558.294 us; speedup 1.0000x reference)
//
#include <hip/hip_runtime.h>

#define NB 4
#define CB 64
#define HB 256
#define WB 256
#define OB 18
#define HWB (HB*WB)
#define TILE 16
#define ICC 8
#define HALFC 32
#define EPSV 1e-5f

__device__ __forceinline__ int reflect_idx(int i, int n) {
    if (i < 0) i = -i;
    if (i >= n) i = 2*n - 2 - i;
    return i;
}

// Async global->LDS DMA, 4 bytes/lane. LDS dst is wave-uniform base + lane*4;
// tile[tid + i*256] satisfies that exactly.
__device__ __forceinline__ void ldsdma4(const float* g, float* l) {
    __builtin_amdgcn_global_load_lds(
        (__attribute__((address_space(1))) unsigned int*)g,
        (__attribute__((address_space(3))) unsigned int*)l, 4, 0, 0);
}

// Transpose weights (18,64,3,3) -> wt[c][o][k]: per channel, the 18 o-slices of
// 9 taps are contiguous, so a wave's o-subset is one contiguous scalar region.
__global__ __launch_bounds__(256) void transpose_w_kernel(
    const float* __restrict__ w, float* __restrict__ wt)
{
    int i = blockIdx.x * 256 + threadIdx.x;
    if (i < OB*CB*9) {
        int o   = i / (CB*9);
        int rem = i - o*CB*9;
        int c   = rem / 9;
        int k   = rem - c*9;
        wt[c*OB*9 + o*9 + k] = w[i];
    }
}

// Issue the 2592-element halo stage for channel-chunk cb into dst (async DMA).
#define STAGE(dst, cb) do {                                            \
    const float* _yb = ybase + (size_t)(cb)*HWB;                       \
    _Pragma("unroll")                                                  \
    for (int _i = 0; _i < 10; ++_i)                                    \
        ldsdma4(_yb + sofs[_i], (dst) + tid + _i*256);                 \
    if (tid < 32) ldsdma4(_yb + sofs[10], (dst) + tid + 2560);         \
} while (0)

// Staging map: element j = tid + 256*i -> channel*HWB + reflected pixel offset.
#define MAKE_SOFS() do {                                               \
    _Pragma("unroll")                                                  \
    for (int _i = 0; _i < 11; ++_i) {                                  \
        int _j  = tid + _i*256;                                        \
        int _jj = (_j < ICC*324) ? _j : 0;                             \
        int _c   = _jj / 324;                                          \
        int _rem = _jj - _c*324;                                       \
        int _rr  = _rem / 18;                                          \
        int _col = _rem - _rr*18;                                      \
        sofs[_i] = _c*HWB + reflect_idx(h0 - 1 + _rr, HB)*WB           \
                          + reflect_idx(w0 - 1 + _col, WB);            \
    }                                                                  \
} while (0)

// Load the 3x6 halo window (4 horizontal pixels) for channel slot ii.
// Rows are 18 floats; (row*18 + c0) is always even -> valid float2 loads.
#define LOADV(tl, ii) do {                                             \
    _Pragma("unroll")                                                  \
    for (int _dy = 0; _dy < 3; ++_dy) {                                \
        const float2* _t2 = (const float2*)((tl) + (ii)*324 + (r+_dy)*18 + c0); \
        float2 _a = _t2[0], _b = _t2[1], _c = _t2[2];                  \
        v[_dy][0]=_a.x; v[_dy][1]=_a.y; v[_dy][2]=_b.x;                \
        v[_dy][3]=_b.y; v[_dy][4]=_c.x; v[_dy][5]=_c.y;                \
    }                                                                  \
} while (0)

// Kernel 1: 3x3x(32 of 64)->18 conv + per-block sum/sumsq partials.
// Lane owns 4 horizontal pixels; the 4 waves split the 18 output channels
// (5,5,4,4). Input channels split 2-way across blocks (grid z = 8) for TLP;
// half 1 writes sigma1 (stashed in the out buffer, dead until apply_kernel).
__global__ __launch_bounds__(256) void conv_stats_kernel(
    const float* __restrict__ y, const float* __restrict__ wt,
    float* __restrict__ sigma0, float* __restrict__ sigma1,
    float* __restrict__ psum, float* __restrict__ psq)
{
    __shared__ float tile[2][ICC*324];
    const int tid = threadIdx.x;
    const int lane = tid & 63, wv = tid >> 6;
    const int r  = lane >> 2;          // pixel row 0..15
    const int c0 = (lane & 3) * 4;     // pixel col base 0,4,8,12
    const int o0 = (wv < 2) ? wv*5 : wv*4 + 2;   // 0,5,10,14
    const bool has5 = (wv < 2);
    const int bx = blockIdx.x, by = blockIdx.y;
    const int n = blockIdx.z >> 1, half = blockIdx.z & 1;
    const int h0 = by * TILE, w0 = bx * TILE;

    int sofs[11];
    MAKE_SOFS();

    const float* ybase = y + ((size_t)n*CB + half*HALFC)*HWB;
    float* const sg = half ? sigma1 : sigma0;

    float acc[4][5];
#pragma unroll
    for (int j = 0; j < 4; ++j)
#pragma unroll
        for (int oi = 0; oi < 5; ++oi) acc[j][oi] = 0.f;

    STAGE(tile[0], 0);
    __syncthreads();

    for (int ci = 0; ci < 4; ++ci) {
        const int cb = ci * ICC;
        if (ci < 3) STAGE(tile[(ci&1)^1], cb + ICC);
        const float* tl = tile[ci&1];
#pragma unroll
        for (int ii = 0; ii < ICC; ++ii) {
            float v[3][6];
            LOADV(tl, ii);
            const float* wp = wt + (half*HALFC + cb + ii)*162 + o0*9;  // 45 uniform
#pragma unroll
            for (int oi = 0; oi < 4; ++oi)
#pragma unroll
                for (int dy = 0; dy < 3; ++dy)
#pragma unroll
                    for (int dx = 0; dx < 3; ++dx) {
                        const float w_ = wp[oi*9 + dy*3 + dx];
#pragma unroll
                        for (int j = 0; j < 4; ++j)
                            acc[j][oi] = fmaf(v[dy][dx+j], w_, acc[j][oi]);
                    }
            if (has5)
#pragma unroll
                for (int dy = 0; dy < 3; ++dy)
#pragma unroll
                    for (int dx = 0; dx < 3; ++dx) {
                        const float w_ = wp[36 + dy*3 + dx];
#pragma unroll
                        for (int j = 0; j < 4; ++j)
                            acc[j][4] = fmaf(v[dy][dx+j], w_, acc[j][4]);
                    }
        }
        __syncthreads();
    }

    const int qbase = (h0 + r)*WB + w0 + c0;
    const int bid = ((n*2 + half)*16 + by)*16 + bx;   // 0..2047

    // Compile-time oi only -> acc stays in registers (rule #20; round-2 spill).
#define EMIT(oi) do {                                                        \
        const int o = o0 + (oi);                                             \
        *(float4*)(sg + ((size_t)n*OB + o)*HWB + qbase) =                    \
            make_float4(acc[0][oi], acc[1][oi], acc[2][oi], acc[3][oi]);     \
        float s  = acc[0][oi] + acc[1][oi] + acc[2][oi] + acc[3][oi];        \
        float s2 = acc[0][oi]*acc[0][oi] + acc[1][oi]*acc[1][oi]             \
                 + acc[2][oi]*acc[2][oi] + acc[3][oi]*acc[3][oi];            \
        for (int off = 32; off > 0; off >>= 1) {                             \
            s  += __shfl_down(s,  off, 64);                                  \
            s2 += __shfl_down(s2, off, 64);                                  \
        }                                                                    \
        if (lane == 0) { psum[o*2048 + bid] = s; psq[o*2048 + bid] = s2; }   \
    } while (0)

    EMIT(0); EMIT(1); EMIT(2); EMIT(3);
    if (has5) EMIT(4);
#undef EMIT
}

// Kernel 2: reduce 2048 partials per channel -> fused scale/shift
__global__ __launch_bounds__(256) void stats_kernel(
    const float* __restrict__ psum, const float* __restrict__ psq,
    const float* __restrict__ gamma, const float* __restrict__ beta,
    float* __restrict__ scale, float* __restrict__ shift)
{
    const int o = blockIdx.x;
    const int t = threadIdx.x;
    float s = 0.f, s2 = 0.f;
#pragma unroll
    for (int i = 0; i < 8; ++i) {
        s  += psum[o*2048 + t + i*256];
        s2 += psq [o*2048 + t + i*256];
    }
    for (int off = 32; off > 0; off >>= 1) {
        s  += __shfl_down(s,  off, 64);
        s2 += __shfl_down(s2, off, 64);
    }
    __shared__ float red[8];
    const int lane = t & 63, wv = t >> 6;
    if (lane == 0) { red[wv] = s; red[wv + 4] = s2; }
    __syncthreads();
    if (t == 0) {
        float S  = red[0] + red[1] + red[2] + red[3];
        float SS = red[4] + red[5] + red[6] + red[7];
        const float cnt = (float)(NB * HWB);
        float mean = S / cnt;
        float var  = SS / cnt - mean*mean;
        float sc = gamma[o] * rsqrtf(var + EPSV);
        scale[o] = sc;
        shift[o] = beta[o] - mean * sc;
    }
}

// Kernel 2.5: normalize + softmax over 18 -> v_map (a required output, and the
// apply kernel re-reads it so each apply block only needs its group's 9 rows).
__global__ __launch_bounds__(256) void softmax_vmap_kernel(
    const float* __restrict__ sigma0, const float* __restrict__ sigma1,
    const float* __restrict__ scale, const float* __restrict__ shift,
    float* __restrict__ vmap)
{
    const int n = blockIdx.y;
    const int q = blockIdx.x * 256 + threadIdx.x;
    float z[OB];
#pragma unroll
    for (int o = 0; o < OB; ++o) {
        const size_t idx = ((size_t)n*OB + o)*HWB + q;
        z[o] = fmaf(sigma0[idx] + sigma1[idx], scale[o], shift[o]);
    }
    float m = z[0];
#pragma unroll
    for (int o = 1; o < OB; ++o) m = fmaxf(m, z[o]);
    float sum = 0.f;
#pragma unroll
    for (int o = 0; o < OB; ++o) { z[o] = __expf(z[o] - m); sum += z[o]; }
    const float rs = 1.f / sum;
#pragma unroll
    for (int o = 0; o < OB; ++o)
        vmap[((size_t)n*OB + o)*HWB + q] = z[o] * rs;
}

// Kernel 3: adaptive filter. Lane owns 4 horizontal pixels; waves split the
// block's 32 channels (2 per wave per chunk). The block's channel half IS one
// softmax group, so only z[4][9] (36 VGPR) of filter weights are needed.
__global__ __launch_bounds__(256) void apply_kernel(
    const float* __restrict__ y, const float* __restrict__ vmap,
    float* __restrict__ out)
{
    __shared__ float tile[2][ICC*324];
    const int tid = threadIdx.x;
    const int lane = tid & 63, wv = tid >> 6;
    const int r  = lane >> 2;
    const int c0 = (lane & 3) * 4;
    const int bx = blockIdx.x, by = blockIdx.y;
    const int n = blockIdx.z >> 1, half = blockIdx.z & 1;  // group g == half
    const int h0 = by * TILE, w0 = bx * TILE;
    const int qbase = (h0 + r)*WB + w0 + c0;

    int sofs[11];
    MAKE_SOFS();

    const float* ybase = y + ((size_t)n*CB + half*HALFC)*HWB;

    STAGE(tile[0], 0);     // async: lands while we load z below

    float z[4][9];
#pragma unroll
    for (int k = 0; k < 9; ++k) {
        const float4 t = *(const float4*)(vmap + ((size_t)n*OB + half*9 + k)*HWB + qbase);
        z[0][k] = t.x; z[1][k] = t.y; z[2][k] = t.z; z[3][k] = t.w;
    }

    float* obase = out + ((size_t)n*CB + half*HALFC)*HWB;
    __syncthreads();       // prologue DMA drained

    for (int ci = 0; ci < 4; ++ci) {
        const int cb = ci * ICC;
        if (ci < 3) STAGE(tile[(ci&1)^1], cb + ICC);
        const float* tl = tile[ci&1];
#pragma unroll
        for (int jj = 0; jj < 2; ++jj) {
            const int ii = 2*wv + jj;             // this wave's channel slot
            float v[3][6];
            LOADV(tl, ii);
            float a0 = 0.f, a1 = 0.f, a2 = 0.f, a3 = 0.f;
#pragma unroll
            for (int dy = 0; dy < 3; ++dy)
#pragma unroll
                for (int dx = 0; dx < 3; ++dx) {
                    const int k = dy*3 + dx;
                    a0 = fmaf(v[dy][dx+0], z[0][k], a0);
                    a1 = fmaf(v[dy][dx+1], z[1][k], a1);
                    a2 = fmaf(v[dy][dx+2], z[2][k], a2);
                    a3 = fmaf(v[dy][dx+3], z[3][k], a3);
                }
            *(float4*)(obase + (size_t)(cb + ii)*HWB + qbase) =
                make_float4(a0, a1, a2, a3);
        }
        __syncthreads();
    }
}

extern "C" void kernel_launch(void* const* d_in, const int* in_sizes, int n_in,
                              void* d_out, int out_size, void* d_ws, size_t ws_size,
                              hipStream_t stream) {
    const float* y     = (const float*)d_in[0];
    const float* w     = (const float*)d_in[1];
    const float* gamma = (const float*)d_in[2];
    const float* beta  = (const float*)d_in[3];
    float* out = (float*)d_out;

    float* sigma0 = (float*)d_ws;                 // 4*18*65536 floats
    float* wt     = sigma0 + (size_t)NB*OB*HWB;   // 10368
    float* psum   = wt + OB*CB*9;                 // 18*2048
    float* psq    = psum + OB*2048;               // 18*2048
    float* scale  = psq  + OB*2048;               // 18
    float* shift  = scale + OB;                   // 18

    float* sigma1 = out;                          // out region is dead until apply
    float* vmap   = out + (size_t)NB*CB*HWB;

    dim3 block(256);
    transpose_w_kernel<<<dim3((OB*CB*9 + 255)/256), block, 0, stream>>>(w, wt);
    conv_stats_kernel<<<dim3(16,16,8), block, 0, stream>>>(y, wt, sigma0, sigma1, psum, psq);
    stats_kernel<<<dim3(OB), block, 0, stream>>>(psum, psq, gamma, beta, scale, shift);
    softmax_vmap_kernel<<<dim3(HWB/256, NB), block, 0, stream>>>(sigma0, sigma1, scale, shift, vmap);
    apply_kernel<<<dim3(16,16,8), block, 0, stream>>>(y, vmap, out);
}

// Round 4
// 393.896 us; speedup vs baseline: 1.4174x; 1.4174x over previous
//
#include <hip/hip_runtime.h>

#define NB 4
#define CB 64
#define HB 256
#define WB 256
#define OB 18
#define HWB (HB*WB)
#define TILE 16
#define ICC 8
#define HALFC 32
#define EPSV 1e-5f

__device__ __forceinline__ int reflect_idx(int i, int n) {
    if (i < 0) i = -i;
    if (i >= n) i = 2*n - 2 - i;
    return i;
}

// Async global->LDS DMA, 4 bytes/lane. LDS dst is wave-uniform base + lane*4;
// tile[tid + i*256] satisfies that exactly.
__device__ __forceinline__ void ldsdma4(const float* g, float* l) {
    __builtin_amdgcn_global_load_lds(
        (__attribute__((address_space(1))) unsigned int*)g,
        (__attribute__((address_space(3))) unsigned int*)l, 4, 0, 0);
}

// Transpose weights (18,64,3,3) -> wt[c][o][k]: per channel, the 18 o-slices of
// 9 taps are contiguous, so a wave's o-subset is one contiguous scalar region.
__global__ __launch_bounds__(256) void transpose_w_kernel(
    const float* __restrict__ w, float* __restrict__ wt)
{
    int i = blockIdx.x * 256 + threadIdx.x;
    if (i < OB*CB*9) {
        int o   = i / (CB*9);
        int rem = i - o*CB*9;
        int c   = rem / 9;
        int k   = rem - c*9;
        wt[c*OB*9 + o*9 + k] = w[i];
    }
}

// Issue the 2592-element halo stage for channel-chunk cb into dst (async DMA).
#define STAGE(dst, cb) do {                                            \
    const float* _yb = ybase + (size_t)(cb)*HWB;                       \
    _Pragma("unroll")                                                  \
    for (int _i = 0; _i < 10; ++_i)                                    \
        ldsdma4(_yb + sofs[_i], (dst) + tid + _i*256);                 \
    if (tid < 32) ldsdma4(_yb + sofs[10], (dst) + tid + 2560);         \
} while (0)

// Staging map: element j = tid + 256*i -> channel*HWB + reflected pixel offset.
#define MAKE_SOFS() do {                                               \
    _Pragma("unroll")                                                  \
    for (int _i = 0; _i < 11; ++_i) {                                  \
        int _j  = tid + _i*256;                                        \
        int _jj = (_j < ICC*324) ? _j : 0;                             \
        int _c   = _jj / 324;                                          \
        int _rem = _jj - _c*324;                                       \
        int _rr  = _rem / 18;                                          \
        int _col = _rem - _rr*18;                                      \
        sofs[_i] = _c*HWB + reflect_idx(h0 - 1 + _rr, HB)*WB           \
                          + reflect_idx(w0 - 1 + _col, WB);            \
    }                                                                  \
} while (0)

// Load the 3x6 halo window (4 horizontal pixels) for channel slot ii.
// Rows are 18 floats; (row*18 + c0) is always even -> valid float2 loads.
#define LOADV(tl, ii) do {                                             \
    _Pragma("unroll")                                                  \
    for (int _dy = 0; _dy < 3; ++_dy) {                                \
        const float2* _t2 = (const float2*)((tl) + (ii)*324 + (r+_dy)*18 + c0); \
        float2 _a = _t2[0], _b = _t2[1], _c = _t2[2];                  \
        v[_dy][0]=_a.x; v[_dy][1]=_a.y; v[_dy][2]=_b.x;                \
        v[_dy][3]=_b.y; v[_dy][4]=_c.x; v[_dy][5]=_c.y;                \
    }                                                                  \
} while (0)

// Kernel 1: 3x3x(32 of 64)->18 conv + per-block sum/sumsq partials.
// Lane owns 4 horizontal pixels; the 4 waves split the 18 output channels
// (5,5,4,4). wv is readfirstlane'd so the weight address is PROVABLY
// wave-uniform -> s_load path (round-2/3 spill was divergent vector loads
// of the weights: VGPR=256, 245MB scratch).
__global__ __launch_bounds__(256) void conv_stats_kernel(
    const float* __restrict__ y, const float* __restrict__ wt,
    float* __restrict__ sigma0, float* __restrict__ sigma1,
    float* __restrict__ psum, float* __restrict__ psq)
{
    __shared__ float tile[2][ICC*324];
    const int tid = threadIdx.x;
    const int lane = tid & 63;
    const int wv = __builtin_amdgcn_readfirstlane(tid >> 6);   // SGPR wave id
    const int r  = lane >> 2;          // pixel row 0..15
    const int c0 = (lane & 3) * 4;     // pixel col base 0,4,8,12
    const int o0 = (wv < 2) ? wv*5 : wv*4 + 2;   // 0,5,10,14 (uniform)
    const bool has5 = (wv < 2);                  // uniform branch
    const int bx = blockIdx.x, by = blockIdx.y;
    const int n = blockIdx.z >> 1, half = blockIdx.z & 1;
    const int h0 = by * TILE, w0 = bx * TILE;

    int sofs[11];
    MAKE_SOFS();

    const float* ybase = y + ((size_t)n*CB + half*HALFC)*HWB;
    float* const sg = half ? sigma1 : sigma0;

    float acc[4][5];
#pragma unroll
    for (int j = 0; j < 4; ++j)
#pragma unroll
        for (int oi = 0; oi < 5; ++oi) acc[j][oi] = 0.f;

    STAGE(tile[0], 0);
    __syncthreads();

    for (int ci = 0; ci < 4; ++ci) {
        const int cb = ci * ICC;
        if (ci < 3) STAGE(tile[(ci&1)^1], cb + ICC);
        const float* tl = tile[ci&1];
#pragma unroll
        for (int ii = 0; ii < ICC; ++ii) {
            float v[3][6];
            LOADV(tl, ii);
            const float* wp = wt + (half*HALFC + cb + ii)*162 + o0*9;  // uniform
#pragma unroll
            for (int oi = 0; oi < 4; ++oi)
#pragma unroll
                for (int dy = 0; dy < 3; ++dy)
#pragma unroll
                    for (int dx = 0; dx < 3; ++dx) {
                        const float w_ = wp[oi*9 + dy*3 + dx];
#pragma unroll
                        for (int j = 0; j < 4; ++j)
                            acc[j][oi] = fmaf(v[dy][dx+j], w_, acc[j][oi]);
                    }
            if (has5)
#pragma unroll
                for (int dy = 0; dy < 3; ++dy)
#pragma unroll
                    for (int dx = 0; dx < 3; ++dx) {
                        const float w_ = wp[36 + dy*3 + dx];
#pragma unroll
                        for (int j = 0; j < 4; ++j)
                            acc[j][4] = fmaf(v[dy][dx+j], w_, acc[j][4]);
                    }
        }
        __syncthreads();
    }

    const int qbase = (h0 + r)*WB + w0 + c0;
    const int bid = ((n*2 + half)*16 + by)*16 + bx;   // 0..2047

    // Compile-time oi only -> acc stays in registers (rule #20).
#define EMIT(oi) do {                                                        \
        const int o = o0 + (oi);                                             \
        *(float4*)(sg + ((size_t)n*OB + o)*HWB + qbase) =                    \
            make_float4(acc[0][oi], acc[1][oi], acc[2][oi], acc[3][oi]);     \
        float s  = acc[0][oi] + acc[1][oi] + acc[2][oi] + acc[3][oi];        \
        float s2 = acc[0][oi]*acc[0][oi] + acc[1][oi]*acc[1][oi]             \
                 + acc[2][oi]*acc[2][oi] + acc[3][oi]*acc[3][oi];            \
        for (int off = 32; off > 0; off >>= 1) {                             \
            s  += __shfl_down(s,  off, 64);                                  \
            s2 += __shfl_down(s2, off, 64);                                  \
        }                                                                    \
        if (lane == 0) { psum[o*2048 + bid] = s; psq[o*2048 + bid] = s2; }   \
    } while (0)

    EMIT(0); EMIT(1); EMIT(2); EMIT(3);
    if (has5) EMIT(4);
#undef EMIT
}

// Kernel 2: reduce 2048 partials per channel -> fused scale/shift
__global__ __launch_bounds__(256) void stats_kernel(
    const float* __restrict__ psum, const float* __restrict__ psq,
    const float* __restrict__ gamma, const float* __restrict__ beta,
    float* __restrict__ scale, float* __restrict__ shift)
{
    const int o = blockIdx.x;
    const int t = threadIdx.x;
    float s = 0.f, s2 = 0.f;
#pragma unroll
    for (int i = 0; i < 8; ++i) {
        s  += psum[o*2048 + t + i*256];
        s2 += psq [o*2048 + t + i*256];
    }
    for (int off = 32; off > 0; off >>= 1) {
        s  += __shfl_down(s,  off, 64);
        s2 += __shfl_down(s2, off, 64);
    }
    __shared__ float red[8];
    const int lane = t & 63, wv = t >> 6;
    if (lane == 0) { red[wv] = s; red[wv + 4] = s2; }
    __syncthreads();
    if (t == 0) {
        float S  = red[0] + red[1] + red[2] + red[3];
        float SS = red[4] + red[5] + red[6] + red[7];
        const float cnt = (float)(NB * HWB);
        float mean = S / cnt;
        float var  = SS / cnt - mean*mean;
        float sc = gamma[o] * rsqrtf(var + EPSV);
        scale[o] = sc;
        shift[o] = beta[o] - mean * sc;
    }
}

// Kernel 2.5: normalize + softmax over 18 -> v_map (a required output; the
// apply kernel re-reads it so each apply block only needs its group's 9 rows).
__global__ __launch_bounds__(256) void softmax_vmap_kernel(
    const float* __restrict__ sigma0, const float* __restrict__ sigma1,
    const float* __restrict__ scale, const float* __restrict__ shift,
    float* __restrict__ vmap)
{
    const int n = blockIdx.y;
    const int q = blockIdx.x * 256 + threadIdx.x;
    float z[OB];
#pragma unroll
    for (int o = 0; o < OB; ++o) {
        const size_t idx = ((size_t)n*OB + o)*HWB + q;
        z[o] = fmaf(sigma0[idx] + sigma1[idx], scale[o], shift[o]);
    }
    float m = z[0];
#pragma unroll
    for (int o = 1; o < OB; ++o) m = fmaxf(m, z[o]);
    float sum = 0.f;
#pragma unroll
    for (int o = 0; o < OB; ++o) { z[o] = __expf(z[o] - m); sum += z[o]; }
    const float rs = 1.f / sum;
#pragma unroll
    for (int o = 0; o < OB; ++o)
        vmap[((size_t)n*OB + o)*HWB + q] = z[o] * rs;
}

// Kernel 3: adaptive filter. Lane owns 4 horizontal pixels; waves split the
// block's 32 channels (2 per wave per chunk). The block's channel half IS one
// softmax group, so only z[4][9] (36 VGPR) of filter weights are needed.
__global__ __launch_bounds__(256) void apply_kernel(
    const float* __restrict__ y, const float* __restrict__ vmap,
    float* __restrict__ out)
{
    __shared__ float tile[2][ICC*324];
    const int tid = threadIdx.x;
    const int lane = tid & 63;
    const int wv = __builtin_amdgcn_readfirstlane(tid >> 6);
    const int r  = lane >> 2;
    const int c0 = (lane & 3) * 4;
    const int bx = blockIdx.x, by = blockIdx.y;
    const int n = blockIdx.z >> 1, half = blockIdx.z & 1;  // group g == half
    const int h0 = by * TILE, w0 = bx * TILE;
    const int qbase = (h0 + r)*WB + w0 + c0;

    int sofs[11];
    MAKE_SOFS();

    const float* ybase = y + ((size_t)n*CB + half*HALFC)*HWB;

    STAGE(tile[0], 0);     // async: lands while we load z below

    float z[4][9];
#pragma unroll
    for (int k = 0; k < 9; ++k) {
        const float4 t = *(const float4*)(vmap + ((size_t)n*OB + half*9 + k)*HWB + qbase);
        z[0][k] = t.x; z[1][k] = t.y; z[2][k] = t.z; z[3][k] = t.w;
    }

    float* obase = out + ((size_t)n*CB + half*HALFC)*HWB;
    __syncthreads();       // prologue DMA drained

    for (int ci = 0; ci < 4; ++ci) {
        const int cb = ci * ICC;
        if (ci < 3) STAGE(tile[(ci&1)^1], cb + ICC);
        const float* tl = tile[ci&1];
#pragma unroll
        for (int jj = 0; jj < 2; ++jj) {
            const int ii = 2*wv + jj;             // uniform channel slot
            float v[3][6];
            LOADV(tl, ii);
            float a0 = 0.f, a1 = 0.f, a2 = 0.f, a3 = 0.f;
#pragma unroll
            for (int dy = 0; dy < 3; ++dy)
#pragma unroll
                for (int dx = 0; dx < 3; ++dx) {
                    const int k = dy*3 + dx;
                    a0 = fmaf(v[dy][dx+0], z[0][k], a0);
                    a1 = fmaf(v[dy][dx+1], z[1][k], a1);
                    a2 = fmaf(v[dy][dx+2], z[2][k], a2);
                    a3 = fmaf(v[dy][dx+3], z[3][k], a3);
                }
            *(float4*)(obase + (size_t)(cb + ii)*HWB + qbase) =
                make_float4(a0, a1, a2, a3);
        }
        __syncthreads();
    }
}

extern "C" void kernel_launch(void* const* d_in, const int* in_sizes, int n_in,
                              void* d_out, int out_size, void* d_ws, size_t ws_size,
                              hipStream_t stream) {
    const float* y     = (const float*)d_in[0];
    const float* w     = (const float*)d_in[1];
    const float* gamma = (const float*)d_in[2];
    const float* beta  = (const float*)d_in[3];
    float* out = (float*)d_out;

    float* sigma0 = (float*)d_ws;                 // 4*18*65536 floats
    float* wt     = sigma0 + (size_t)NB*OB*HWB;   // 10368
    float* psum   = wt + OB*CB*9;                 // 18*2048
    float* psq    = psum + OB*2048;               // 18*2048
    float* scale  = psq  + OB*2048;               // 18
    float* shift  = scale + OB;                   // 18

    float* sigma1 = out;                          // out region is dead until apply
    float* vmap   = out + (size_t)NB*CB*HWB;

    dim3 block(256);
    transpose_w_kernel<<<dim3((OB*CB*9 + 255)/256), block, 0, stream>>>(w, wt);
    conv_stats_kernel<<<dim3(16,16,8), block, 0, stream>>>(y, wt, sigma0, sigma1, psum, psq);
    stats_kernel<<<dim3(OB), block, 0, stream>>>(psum, psq, gamma, beta, scale, shift);
    softmax_vmap_kernel<<<dim3(HWB/256, NB), block, 0, stream>>>(sigma0, sigma1, scale, shift, vmap);
    apply_kernel<<<dim3(16,16,8), block, 0, stream>>>(y, vmap, out);
}

// Round 5
// 332.318 us; speedup vs baseline: 1.6800x; 1.1853x over previous
//
#include <hip/hip_runtime.h>

#define NB 4
#define CB 64
#define HB 256
#define WB 256
#define OB 18
#define HWB (HB*WB)
#define TILE 16
#define ICC 8
#define HALFC 32
#define EPSV 1e-5f

__device__ __forceinline__ int reflect_idx(int i, int n) {
    if (i < 0) i = -i;
    if (i >= n) i = 2*n - 2 - i;
    return i;
}

// Async global->LDS DMA, 4 bytes/lane. LDS dst is wave-uniform base + lane*4;
// tile[tid + i*256] satisfies that exactly.
__device__ __forceinline__ void ldsdma4(const float* g, float* l) {
    __builtin_amdgcn_global_load_lds(
        (__attribute__((address_space(1))) unsigned int*)g,
        (__attribute__((address_space(3))) unsigned int*)l, 4, 0, 0);
}

// Transpose weights (18,64,3,3) -> wt[c][o][k] so the conv reads 162
// contiguous floats per input channel (block-uniform -> s_load path).
__global__ __launch_bounds__(256) void transpose_w_kernel(
    const float* __restrict__ w, float* __restrict__ wt)
{
    int i = blockIdx.x * 256 + threadIdx.x;
    if (i < OB*CB*9) {
        int o   = i / (CB*9);
        int rem = i - o*CB*9;
        int c   = rem / 9;
        int k   = rem - c*9;
        wt[c*OB*9 + o*9 + k] = w[i];
    }
}

// Issue the 2592-element halo stage for channel-chunk cb into dst (async DMA).
#define STAGE(dst, cb) do {                                            \
    const float* _yb = ybase + (size_t)(cb)*HWB;                       \
    _Pragma("unroll")                                                  \
    for (int _i = 0; _i < 10; ++_i)                                    \
        ldsdma4(_yb + sofs[_i], (dst) + tid + _i*256);                 \
    if (tid < 32) ldsdma4(_yb + sofs[10], (dst) + tid + 2560);         \
} while (0)

// Staging map: element j = tid + 256*i -> channel*HWB + reflected pixel offset.
#define MAKE_SOFS() do {                                               \
    _Pragma("unroll")                                                  \
    for (int _i = 0; _i < 11; ++_i) {                                  \
        int _j  = tid + _i*256;                                        \
        int _jj = (_j < ICC*324) ? _j : 0;                             \
        int _c   = _jj / 324;                                          \
        int _rem = _jj - _c*324;                                       \
        int _rr  = _rem / 18;                                          \
        int _col = _rem - _rr*18;                                      \
        sofs[_i] = _c*HWB + reflect_idx(h0 - 1 + _rr, HB)*WB           \
                          + reflect_idx(w0 - 1 + _col, WB);            \
    }                                                                  \
} while (0)

// Kernel 1: 3x3x(32 of 64)->18 conv + per-block sum/sumsq partials.
// Round-1 proven structure (1 px/thread, acc[18], VGPR=48, uniform weights);
// input channels split 2-way across grid z for TLP (2048 blocks, ~7/CU).
__global__ __launch_bounds__(256) void conv_stats_kernel(
    const float* __restrict__ y, const float* __restrict__ wt,
    float* __restrict__ sigma0, float* __restrict__ sigma1,
    float* __restrict__ psum, float* __restrict__ psq)
{
    __shared__ float tile[2][ICC*324];
    __shared__ float red[4][36];
    const int tid = threadIdx.x;
    const int tx = tid & 15, ty = tid >> 4;
    const int bx = blockIdx.x, by = blockIdx.y;
    const int n = blockIdx.z >> 1, half = blockIdx.z & 1;
    const int h0 = by * TILE, w0 = bx * TILE;

    int sofs[11];
    MAKE_SOFS();

    const float* ybase = y + ((size_t)n*CB + half*HALFC)*HWB;
    float* const sg = half ? sigma1 : sigma0;

    float acc[OB];
#pragma unroll
    for (int o = 0; o < OB; ++o) acc[o] = 0.f;

    STAGE(tile[0], 0);
    __syncthreads();

    for (int ci = 0; ci < 4; ++ci) {
        const int cb = ci * ICC;
        if (ci < 3) STAGE(tile[(ci&1)^1], cb + ICC);
        const float* tl = tile[ci&1];
#pragma unroll
        for (int ii = 0; ii < ICC; ++ii) {
            float v[9];
#pragma unroll
            for (int dy = 0; dy < 3; ++dy)
#pragma unroll
                for (int dx = 0; dx < 3; ++dx)
                    v[dy*3+dx] = tl[ii*324 + (ty+dy)*18 + tx+dx];
            const float* wp = wt + (half*HALFC + cb + ii)*162;  // uniform
#pragma unroll
            for (int o = 0; o < OB; ++o)
#pragma unroll
                for (int k = 0; k < 9; ++k)
                    acc[o] = fmaf(v[k], wp[o*9 + k], acc[o]);
        }
        __syncthreads();
    }

    const int q = (h0 + ty)*WB + (w0 + tx);
#pragma unroll
    for (int o = 0; o < OB; ++o)
        sg[((size_t)n*OB + o)*HWB + q] = acc[o];

    const int lane = tid & 63, wv = tid >> 6;
#pragma unroll
    for (int o = 0; o < OB; ++o) {
        float s  = acc[o];
        float s2 = acc[o]*acc[o];
        for (int off = 32; off > 0; off >>= 1) {
            s  += __shfl_down(s,  off, 64);
            s2 += __shfl_down(s2, off, 64);
        }
        if (lane == 0) { red[wv][o] = s; red[wv][o + OB] = s2; }
    }
    __syncthreads();
    if (tid < 36) {
        float t = red[0][tid] + red[1][tid] + red[2][tid] + red[3][tid];
        const int bid = ((n*2 + half)*16 + by)*16 + bx;   // 0..2047
        if (tid < OB) psum[tid*2048 + bid] = t;
        else          psq[(tid-OB)*2048 + bid] = t;
    }
}

// Kernel 2: reduce 2048 partials per channel -> fused scale/shift
__global__ __launch_bounds__(256) void stats_kernel(
    const float* __restrict__ psum, const float* __restrict__ psq,
    const float* __restrict__ gamma, const float* __restrict__ beta,
    float* __restrict__ scale, float* __restrict__ shift)
{
    const int o = blockIdx.x;
    const int t = threadIdx.x;
    float s = 0.f, s2 = 0.f;
#pragma unroll
    for (int i = 0; i < 8; ++i) {
        s  += psum[o*2048 + t + i*256];
        s2 += psq [o*2048 + t + i*256];
    }
    for (int off = 32; off > 0; off >>= 1) {
        s  += __shfl_down(s,  off, 64);
        s2 += __shfl_down(s2, off, 64);
    }
    __shared__ float red[8];
    const int lane = t & 63, wv = t >> 6;
    if (lane == 0) { red[wv] = s; red[wv + 4] = s2; }
    __syncthreads();
    if (t == 0) {
        float S  = red[0] + red[1] + red[2] + red[3];
        float SS = red[4] + red[5] + red[6] + red[7];
        const float cnt = (float)(NB * HWB);
        float mean = S / cnt;
        float var  = SS / cnt - mean*mean;
        float sc = gamma[o] * rsqrtf(var + EPSV);
        scale[o] = sc;
        shift[o] = beta[o] - mean * sc;
    }
}

// Kernel 2.5: normalize + softmax over 18 -> v_map (a required output; the
// apply kernel re-reads it so each apply block only needs its group's 9 rows).
__global__ __launch_bounds__(256) void softmax_vmap_kernel(
    const float* __restrict__ sigma0, const float* __restrict__ sigma1,
    const float* __restrict__ scale, const float* __restrict__ shift,
    float* __restrict__ vmap)
{
    const int n = blockIdx.y;
    const int q = blockIdx.x * 256 + threadIdx.x;
    float z[OB];
#pragma unroll
    for (int o = 0; o < OB; ++o) {
        const size_t idx = ((size_t)n*OB + o)*HWB + q;
        z[o] = fmaf(sigma0[idx] + sigma1[idx], scale[o], shift[o]);
    }
    float m = z[0];
#pragma unroll
    for (int o = 1; o < OB; ++o) m = fmaxf(m, z[o]);
    float sum = 0.f;
#pragma unroll
    for (int o = 0; o < OB; ++o) { z[o] = __expf(z[o] - m); sum += z[o]; }
    const float rs = 1.f / sum;
#pragma unroll
    for (int o = 0; o < OB; ++o)
        vmap[((size_t)n*OB + o)*HWB + q] = z[o] * rs;
}

// Kernel 3: adaptive filter. Round-1 per-thread structure (1 px/thread),
// 32 channels per block via grid-z split; the block's channel half IS one
// softmax group -> only z[9] filter weights needed (low VGPR, high occupancy).
__global__ __launch_bounds__(256) void apply_kernel(
    const float* __restrict__ y, const float* __restrict__ vmap,
    float* __restrict__ out)
{
    __shared__ float tile[2][ICC*324];
    const int tid = threadIdx.x;
    const int tx = tid & 15, ty = tid >> 4;
    const int bx = blockIdx.x, by = blockIdx.y;
    const int n = blockIdx.z >> 1, half = blockIdx.z & 1;  // group g == half
    const int h0 = by * TILE, w0 = bx * TILE;
    const int q = (h0 + ty)*WB + (w0 + tx);

    int sofs[11];
    MAKE_SOFS();

    const float* ybase = y + ((size_t)n*CB + half*HALFC)*HWB;

    STAGE(tile[0], 0);     // async: lands while we load z below

    float z9[9];
#pragma unroll
    for (int k = 0; k < 9; ++k)
        z9[k] = vmap[((size_t)n*OB + half*9 + k)*HWB + q];

    float* obase = out + ((size_t)n*CB + half*HALFC)*HWB;
    __syncthreads();       // prologue DMA drained

    for (int ci = 0; ci < 4; ++ci) {
        const int cb = ci * ICC;
        if (ci < 3) STAGE(tile[(ci&1)^1], cb + ICC);
        const float* tl = tile[ci&1];
#pragma unroll
        for (int ii = 0; ii < ICC; ++ii) {
            float a = 0.f;
#pragma unroll
            for (int dy = 0; dy < 3; ++dy)
#pragma unroll
                for (int dx = 0; dx < 3; ++dx)
                    a = fmaf(tl[ii*324 + (ty+dy)*18 + tx+dx], z9[dy*3+dx], a);
            obase[(size_t)(cb + ii)*HWB + q] = a;
        }
        __syncthreads();
    }
}

extern "C" void kernel_launch(void* const* d_in, const int* in_sizes, int n_in,
                              void* d_out, int out_size, void* d_ws, size_t ws_size,
                              hipStream_t stream) {
    const float* y     = (const float*)d_in[0];
    const float* w     = (const float*)d_in[1];
    const float* gamma = (const float*)d_in[2];
    const float* beta  = (const float*)d_in[3];
    float* out = (float*)d_out;

    float* sigma0 = (float*)d_ws;                 // 4*18*65536 floats
    float* wt     = sigma0 + (size_t)NB*OB*HWB;   // 10368
    float* psum   = wt + OB*CB*9;                 // 18*2048
    float* psq    = psum + OB*2048;               // 18*2048
    float* scale  = psq  + OB*2048;               // 18
    float* shift  = scale + OB;                   // 18

    float* sigma1 = out;                          // out region is dead until apply
    float* vmap   = out + (size_t)NB*CB*HWB;

    dim3 block(256);
    transpose_w_kernel<<<dim3((OB*CB*9 + 255)/256), block, 0, stream>>>(w, wt);
    conv_stats_kernel<<<dim3(16,16,8), block, 0, stream>>>(y, wt, sigma0, sigma1, psum, psq);
    stats_kernel<<<dim3(OB), block, 0, stream>>>(psum, psq, gamma, beta, scale, shift);
    softmax_vmap_kernel<<<dim3(HWB/256, NB), block, 0, stream>>>(sigma0, sigma1, scale, shift, vmap);
    apply_kernel<<<dim3(16,16,8), block, 0, stream>>>(y, vmap, out);
}

// Round 6
// 285.709 us; speedup vs baseline: 1.9541x; 1.1631x over previous
//
#include <hip/hip_runtime.h>

#define NB 4
#define CB 64
#define HB 256
#define WB 256
#define OB 18
#define HWB (HB*WB)
#define TILE 16
#define HALFC 32
#define EPSV 1e-5f

__device__ __forceinline__ int reflect_idx(int i, int n) {
    if (i < 0) i = -i;
    if (i >= n) i = 2*n - 2 - i;
    return i;
}

// Transpose weights (18,64,3,3) -> wt[c][o][k] so the conv reads 162
// contiguous floats per input channel (block-uniform -> s_load path).
__global__ __launch_bounds__(256) void transpose_w_kernel(
    const float* __restrict__ w, float* __restrict__ wt)
{
    int i = blockIdx.x * 256 + threadIdx.x;
    if (i < OB*CB*9) {
        int o   = i / (CB*9);
        int rem = i - o*CB*9;
        int c   = rem / 9;
        int k   = rem - c*9;
        wt[c*OB*9 + o*9 + k] = w[i];
    }
}

// The 9 reflect-padded tap offsets for pixel (h,w) -- channel-invariant,
// computed ONCE; per channel only the (uniform) base pointer moves.
#define MAKE_OFFS(h, w) do {                                           \
    int _ro[3], _co[3];                                                \
    _Pragma("unroll")                                                  \
    for (int _d = 0; _d < 3; ++_d) {                                   \
        _ro[_d] = reflect_idx((h) - 1 + _d, HB) * WB;                  \
        _co[_d] = reflect_idx((w) - 1 + _d, WB);                       \
    }                                                                  \
    _Pragma("unroll")                                                  \
    for (int _dy = 0; _dy < 3; ++_dy)                                  \
        _Pragma("unroll")                                              \
        for (int _dx = 0; _dx < 3; ++_dx)                              \
            offs[_dy*3+_dx] = _ro[_dy] + _co[_dx];                     \
} while (0)

// Kernel 1: 3x3x(32 of 64)->18 conv + per-block sum/sumsq partials.
// NO LDS staging: the 1.3KB/channel tap window is L1-resident; direct
// global loads remove all barriers/DMA -> waves free-run, stalls
// decorrelate across the 32 waves/CU (r5 showed barrier convoys, not
// occupancy, were the limiter).
__global__ __launch_bounds__(256) void conv_stats_kernel(
    const float* __restrict__ y, const float* __restrict__ wt,
    float* __restrict__ sigma0, float* __restrict__ sigma1,
    float* __restrict__ psum, float* __restrict__ psq)
{
    __shared__ float red[4][36];
    const int tid = threadIdx.x;
    const int tx = tid & 15, ty = tid >> 4;
    const int bx = blockIdx.x, by = blockIdx.y;
    const int n = blockIdx.z >> 1, half = blockIdx.z & 1;
    const int h = by*TILE + ty, w = bx*TILE + tx;

    int offs[9];
    MAKE_OFFS(h, w);

    const float* ybase = y + ((size_t)n*CB + half*HALFC)*HWB;
    float* const sg = half ? sigma1 : sigma0;

    float acc[OB];
#pragma unroll
    for (int o = 0; o < OB; ++o) acc[o] = 0.f;

#pragma unroll 2
    for (int c = 0; c < HALFC; ++c) {
        const float* p = ybase + (size_t)c*HWB;
        float v[9];
#pragma unroll
        for (int k = 0; k < 9; ++k) v[k] = p[offs[k]];
        const float* wp = wt + (half*HALFC + c)*162;   // uniform -> s_load
#pragma unroll
        for (int o = 0; o < OB; ++o)
#pragma unroll
            for (int k = 0; k < 9; ++k)
                acc[o] = fmaf(v[k], wp[o*9 + k], acc[o]);
    }

    const int q = h*WB + w;
#pragma unroll
    for (int o = 0; o < OB; ++o)
        sg[((size_t)n*OB + o)*HWB + q] = acc[o];

    const int lane = tid & 63, wv = tid >> 6;
#pragma unroll
    for (int o = 0; o < OB; ++o) {
        float s  = acc[o];
        float s2 = acc[o]*acc[o];
        for (int off = 32; off > 0; off >>= 1) {
            s  += __shfl_down(s,  off, 64);
            s2 += __shfl_down(s2, off, 64);
        }
        if (lane == 0) { red[wv][o] = s; red[wv][o + OB] = s2; }
    }
    __syncthreads();
    if (tid < 36) {
        float t = red[0][tid] + red[1][tid] + red[2][tid] + red[3][tid];
        const int bid = ((n*2 + half)*16 + by)*16 + bx;   // 0..2047
        if (tid < OB) psum[tid*2048 + bid] = t;
        else          psq[(tid-OB)*2048 + bid] = t;
    }
}

// Kernel 2: reduce 2048 partials per channel -> fused scale/shift
__global__ __launch_bounds__(256) void stats_kernel(
    const float* __restrict__ psum, const float* __restrict__ psq,
    const float* __restrict__ gamma, const float* __restrict__ beta,
    float* __restrict__ scale, float* __restrict__ shift)
{
    const int o = blockIdx.x;
    const int t = threadIdx.x;
    float s = 0.f, s2 = 0.f;
#pragma unroll
    for (int i = 0; i < 8; ++i) {
        s  += psum[o*2048 + t + i*256];
        s2 += psq [o*2048 + t + i*256];
    }
    for (int off = 32; off > 0; off >>= 1) {
        s  += __shfl_down(s,  off, 64);
        s2 += __shfl_down(s2, off, 64);
    }
    __shared__ float red[8];
    const int lane = t & 63, wv = t >> 6;
    if (lane == 0) { red[wv] = s; red[wv + 4] = s2; }
    __syncthreads();
    if (t == 0) {
        float S  = red[0] + red[1] + red[2] + red[3];
        float SS = red[4] + red[5] + red[6] + red[7];
        const float cnt = (float)(NB * HWB);
        float mean = S / cnt;
        float var  = SS / cnt - mean*mean;
        float sc = gamma[o] * rsqrtf(var + EPSV);
        scale[o] = sc;
        shift[o] = beta[o] - mean * sc;
    }
}

// Kernel 2.5: normalize + softmax over 18 -> v_map (a required output; the
// apply kernel re-reads it so each apply block only needs its group's 9 rows).
__global__ __launch_bounds__(256) void softmax_vmap_kernel(
    const float* __restrict__ sigma0, const float* __restrict__ sigma1,
    const float* __restrict__ scale, const float* __restrict__ shift,
    float* __restrict__ vmap)
{
    const int n = blockIdx.y;
    const int q = blockIdx.x * 256 + threadIdx.x;
    float z[OB];
#pragma unroll
    for (int o = 0; o < OB; ++o) {
        const size_t idx = ((size_t)n*OB + o)*HWB + q;
        z[o] = fmaf(sigma0[idx] + sigma1[idx], scale[o], shift[o]);
    }
    float m = z[0];
#pragma unroll
    for (int o = 1; o < OB; ++o) m = fmaxf(m, z[o]);
    float sum = 0.f;
#pragma unroll
    for (int o = 0; o < OB; ++o) { z[o] = __expf(z[o] - m); sum += z[o]; }
    const float rs = 1.f / sum;
#pragma unroll
    for (int o = 0; o < OB; ++o)
        vmap[((size_t)n*OB + o)*HWB + q] = z[o] * rs;
}

// Kernel 3: adaptive filter, direct-load (no LDS, no barriers). Per channel:
// 9 L1-resident tap loads x z9 weights -> 1 store. Block's channel half IS
// one softmax group -> only z9[9] needed.
__global__ __launch_bounds__(256) void apply_kernel(
    const float* __restrict__ y, const float* __restrict__ vmap,
    float* __restrict__ out)
{
    const int tid = threadIdx.x;
    const int tx = tid & 15, ty = tid >> 4;
    const int bx = blockIdx.x, by = blockIdx.y;
    const int n = blockIdx.z >> 1, half = blockIdx.z & 1;  // group g == half
    const int h = by*TILE + ty, w = bx*TILE + tx;
    const int q = h*WB + w;

    int offs[9];
    MAKE_OFFS(h, w);

    const float* ybase = y + ((size_t)n*CB + half*HALFC)*HWB;

    float z9[9];
#pragma unroll
    for (int k = 0; k < 9; ++k)
        z9[k] = vmap[((size_t)n*OB + half*9 + k)*HWB + q];

    float* obase = out + ((size_t)n*CB + half*HALFC)*HWB;

#pragma unroll 4
    for (int c = 0; c < HALFC; ++c) {
        const float* p = ybase + (size_t)c*HWB;
        float a = 0.f;
#pragma unroll
        for (int k = 0; k < 9; ++k)
            a = fmaf(p[offs[k]], z9[k], a);
        obase[(size_t)c*HWB + q] = a;
    }
}

extern "C" void kernel_launch(void* const* d_in, const int* in_sizes, int n_in,
                              void* d_out, int out_size, void* d_ws, size_t ws_size,
                              hipStream_t stream) {
    const float* y     = (const float*)d_in[0];
    const float* w     = (const float*)d_in[1];
    const float* gamma = (const float*)d_in[2];
    const float* beta  = (const float*)d_in[3];
    float* out = (float*)d_out;

    float* sigma0 = (float*)d_ws;                 // 4*18*65536 floats
    float* wt     = sigma0 + (size_t)NB*OB*HWB;   // 10368
    float* psum   = wt + OB*CB*9;                 // 18*2048
    float* psq    = psum + OB*2048;               // 18*2048
    float* scale  = psq  + OB*2048;               // 18
    float* shift  = scale + OB;                   // 18

    float* sigma1 = out;                          // out region is dead until apply
    float* vmap   = out + (size_t)NB*CB*HWB;

    dim3 block(256);
    transpose_w_kernel<<<dim3((OB*CB*9 + 255)/256), block, 0, stream>>>(w, wt);
    conv_stats_kernel<<<dim3(16,16,8), block, 0, stream>>>(y, wt, sigma0, sigma1, psum, psq);
    stats_kernel<<<dim3(OB), block, 0, stream>>>(psum, psq, gamma, beta, scale, shift);
    softmax_vmap_kernel<<<dim3(HWB/256, NB), block, 0, stream>>>(sigma0, sigma1, scale, shift, vmap);
    apply_kernel<<<dim3(16,16,8), block, 0, stream>>>(y, vmap, out);
}

// Round 7
// 255.836 us; speedup vs baseline: 2.1822x; 1.1168x over previous
//
#include <hip/hip_runtime.h>

#define NB 4
#define CB 64
#define HB 256
#define WB 256
#define OB 18
#define HWB (HB*WB)
#define TILE 16
#define HALFC 32
#define EPSV 1e-5f

__device__ __forceinline__ int reflect_idx(int i, int n) {
    if (i < 0) i = -i;
    if (i >= n) i = 2*n - 2 - i;
    return i;
}

// Transpose weights (18,64,3,3) -> wt[c][o][k] so the conv reads 162
// contiguous floats per input channel (block-uniform -> s_load path).
__global__ __launch_bounds__(256) void transpose_w_kernel(
    const float* __restrict__ w, float* __restrict__ wt)
{
    int i = blockIdx.x * 256 + threadIdx.x;
    if (i < OB*CB*9) {
        int o   = i / (CB*9);
        int rem = i - o*CB*9;
        int c   = rem / 9;
        int k   = rem - c*9;
        wt[c*OB*9 + o*9 + k] = w[i];
    }
}

// 12 reflect-padded tap offsets covering TWO vertical pixels (rows h,h+1):
// tap rows h-1..h+2, cols w-1..w+1. Channel-invariant; computed once.
#define MAKE_OFFS12(h, w) do {                                         \
    int _ro[4], _co[3];                                                \
    _Pragma("unroll")                                                  \
    for (int _d = 0; _d < 4; ++_d)                                     \
        _ro[_d] = reflect_idx((h) - 1 + _d, HB) * WB;                  \
    _Pragma("unroll")                                                  \
    for (int _d = 0; _d < 3; ++_d)                                     \
        _co[_d] = reflect_idx((w) - 1 + _d, WB);                       \
    _Pragma("unroll")                                                  \
    for (int _dy = 0; _dy < 4; ++_dy)                                  \
        _Pragma("unroll")                                              \
        for (int _dx = 0; _dx < 3; ++_dx)                              \
            offs[_dy*3+_dx] = _ro[_dy] + _co[_dx];                     \
} while (0)

// Kernel 1: 3x3x(32 of 64)->18 conv + per-block sum/sumsq partials.
// Direct global loads (L1-resident taps, no LDS/barriers — r6 win).
// 2 vertical px/thread: 12 tap loads serve 2 pixels, and every scalar
// weight dword feeds 2 FMAs -> lgkmcnt/vmcnt wait per FMA halves.
__global__ __launch_bounds__(256) void conv_stats_kernel(
    const float* __restrict__ y, const float* __restrict__ wt,
    float* __restrict__ sigma0, float* __restrict__ sigma1,
    float* __restrict__ psum, float* __restrict__ psq)
{
    __shared__ float red[4][36];
    const int tid = threadIdx.x;
    const int tx = tid & 15, ty = tid >> 4;        // ty 0..15
    const int bx = blockIdx.x, by = blockIdx.y;
    const int n = blockIdx.z >> 1, half = blockIdx.z & 1;
    const int h = by*32 + 2*ty;                    // first of 2 rows
    const int w = bx*TILE + tx;

    int offs[12];
    MAKE_OFFS12(h, w);

    const float* ybase = y + ((size_t)n*CB + half*HALFC)*HWB;
    float* const sg = half ? sigma1 : sigma0;

    float acc0[OB], acc1[OB];
#pragma unroll
    for (int o = 0; o < OB; ++o) { acc0[o] = 0.f; acc1[o] = 0.f; }

#pragma unroll 2
    for (int c = 0; c < HALFC; ++c) {
        const float* p = ybase + (size_t)c*HWB;
        float v[12];
#pragma unroll
        for (int k = 0; k < 12; ++k) v[k] = p[offs[k]];
        const float* wp = wt + (half*HALFC + c)*162;   // uniform -> s_load
#pragma unroll
        for (int o = 0; o < OB; ++o)
#pragma unroll
            for (int dy = 0; dy < 3; ++dy)
#pragma unroll
                for (int dx = 0; dx < 3; ++dx) {
                    const float w_ = wp[o*9 + dy*3 + dx];
                    acc0[o] = fmaf(v[dy*3 + dx],     w_, acc0[o]);
                    acc1[o] = fmaf(v[(dy+1)*3 + dx], w_, acc1[o]);
                }
    }

    const int q = h*WB + w;
#pragma unroll
    for (int o = 0; o < OB; ++o) {
        const size_t b = ((size_t)n*OB + o)*HWB + q;
        sg[b]      = acc0[o];
        sg[b + WB] = acc1[o];
    }

    const int lane = tid & 63, wv = tid >> 6;
#pragma unroll
    for (int o = 0; o < OB; ++o) {
        float s  = acc0[o] + acc1[o];
        float s2 = acc0[o]*acc0[o] + acc1[o]*acc1[o];
        for (int off = 32; off > 0; off >>= 1) {
            s  += __shfl_down(s,  off, 64);
            s2 += __shfl_down(s2, off, 64);
        }
        if (lane == 0) { red[wv][o] = s; red[wv][o + OB] = s2; }
    }
    __syncthreads();
    if (tid < 36) {
        float t = red[0][tid] + red[1][tid] + red[2][tid] + red[3][tid];
        const int bid = ((n*2 + half)*8 + by)*16 + bx;   // 0..1023
        if (tid < OB) psum[tid*1024 + bid] = t;
        else          psq[(tid-OB)*1024 + bid] = t;
    }
}

// Kernel 2: reduce 1024 partials per channel -> fused scale/shift
__global__ __launch_bounds__(256) void stats_kernel(
    const float* __restrict__ psum, const float* __restrict__ psq,
    const float* __restrict__ gamma, const float* __restrict__ beta,
    float* __restrict__ scale, float* __restrict__ shift)
{
    const int o = blockIdx.x;
    const int t = threadIdx.x;
    float s = 0.f, s2 = 0.f;
#pragma unroll
    for (int i = 0; i < 4; ++i) {
        s  += psum[o*1024 + t + i*256];
        s2 += psq [o*1024 + t + i*256];
    }
    for (int off = 32; off > 0; off >>= 1) {
        s  += __shfl_down(s,  off, 64);
        s2 += __shfl_down(s2, off, 64);
    }
    __shared__ float red[8];
    const int lane = t & 63, wv = t >> 6;
    if (lane == 0) { red[wv] = s; red[wv + 4] = s2; }
    __syncthreads();
    if (t == 0) {
        float S  = red[0] + red[1] + red[2] + red[3];
        float SS = red[4] + red[5] + red[6] + red[7];
        const float cnt = (float)(NB * HWB);
        float mean = S / cnt;
        float var  = SS / cnt - mean*mean;
        float sc = gamma[o] * rsqrtf(var + EPSV);
        scale[o] = sc;
        shift[o] = beta[o] - mean * sc;
    }
}

// Kernel 2.5: normalize + softmax over 18 -> v_map (a required output; the
// apply kernel re-reads it so each apply block only needs its group's 9 rows).
__global__ __launch_bounds__(256) void softmax_vmap_kernel(
    const float* __restrict__ sigma0, const float* __restrict__ sigma1,
    const float* __restrict__ scale, const float* __restrict__ shift,
    float* __restrict__ vmap)
{
    const int n = blockIdx.y;
    const int q = blockIdx.x * 256 + threadIdx.x;
    float z[OB];
#pragma unroll
    for (int o = 0; o < OB; ++o) {
        const size_t idx = ((size_t)n*OB + o)*HWB + q;
        z[o] = fmaf(sigma0[idx] + sigma1[idx], scale[o], shift[o]);
    }
    float m = z[0];
#pragma unroll
    for (int o = 1; o < OB; ++o) m = fmaxf(m, z[o]);
    float sum = 0.f;
#pragma unroll
    for (int o = 0; o < OB; ++o) { z[o] = __expf(z[o] - m); sum += z[o]; }
    const float rs = 1.f / sum;
#pragma unroll
    for (int o = 0; o < OB; ++o)
        vmap[((size_t)n*OB + o)*HWB + q] = z[o] * rs;
}

// Kernel 3: adaptive filter, direct-load, 2 vertical px/thread:
// per channel 12 tap loads -> 18 FMAs -> 2 stores. Block's channel half IS
// one softmax group -> only z[2][9] filter weights needed.
__global__ __launch_bounds__(256) void apply_kernel(
    const float* __restrict__ y, const float* __restrict__ vmap,
    float* __restrict__ out)
{
    const int tid = threadIdx.x;
    const int tx = tid & 15, ty = tid >> 4;
    const int bx = blockIdx.x, by = blockIdx.y;
    const int n = blockIdx.z >> 1, half = blockIdx.z & 1;  // group g == half
    const int h = by*32 + 2*ty;
    const int w = bx*TILE + tx;
    const int q = h*WB + w;

    int offs[12];
    MAKE_OFFS12(h, w);

    const float* ybase = y + ((size_t)n*CB + half*HALFC)*HWB;

    float z0[9], z1[9];
#pragma unroll
    for (int k = 0; k < 9; ++k) {
        const size_t b = ((size_t)n*OB + half*9 + k)*HWB + q;
        z0[k] = vmap[b];
        z1[k] = vmap[b + WB];
    }

    float* obase = out + ((size_t)n*CB + half*HALFC)*HWB;

#pragma unroll 2
    for (int c = 0; c < HALFC; ++c) {
        const float* p = ybase + (size_t)c*HWB;
        float v[12];
#pragma unroll
        for (int k = 0; k < 12; ++k) v[k] = p[offs[k]];
        float a0 = 0.f, a1 = 0.f;
#pragma unroll
        for (int dy = 0; dy < 3; ++dy)
#pragma unroll
            for (int dx = 0; dx < 3; ++dx) {
                const int k = dy*3 + dx;
                a0 = fmaf(v[dy*3 + dx],     z0[k], a0);
                a1 = fmaf(v[(dy+1)*3 + dx], z1[k], a1);
            }
        const size_t b = (size_t)c*HWB + q;
        obase[b]      = a0;
        obase[b + WB] = a1;
    }
}

extern "C" void kernel_launch(void* const* d_in, const int* in_sizes, int n_in,
                              void* d_out, int out_size, void* d_ws, size_t ws_size,
                              hipStream_t stream) {
    const float* y     = (const float*)d_in[0];
    const float* w     = (const float*)d_in[1];
    const float* gamma = (const float*)d_in[2];
    const float* beta  = (const float*)d_in[3];
    float* out = (float*)d_out;

    float* sigma0 = (float*)d_ws;                 // 4*18*65536 floats
    float* wt     = sigma0 + (size_t)NB*OB*HWB;   // 10368
    float* psum   = wt + OB*CB*9;                 // 18*1024
    float* psq    = psum + OB*1024;               // 18*1024
    float* scale  = psq  + OB*1024;               // 18
    float* shift  = scale + OB;                   // 18

    float* sigma1 = out;                          // out region is dead until apply
    float* vmap   = out + (size_t)NB*CB*HWB;

    dim3 block(256);
    transpose_w_kernel<<<dim3((OB*CB*9 + 255)/256), block, 0, stream>>>(w, wt);
    conv_stats_kernel<<<dim3(16,8,8), block, 0, stream>>>(y, wt, sigma0, sigma1, psum, psq);
    stats_kernel<<<dim3(OB), block, 0, stream>>>(psum, psq, gamma, beta, scale, shift);
    softmax_vmap_kernel<<<dim3(HWB/256, NB), block, 0, stream>>>(sigma0, sigma1, scale, shift, vmap);
    apply_kernel<<<dim3(16,8,8), block, 0, stream>>>(y, vmap, out);
}